// Round 8
// baseline (85.584 us; speedup 1.0000x reference)
//
#include <hip/hip_runtime.h>

#define TPB 256

typedef __attribute__((ext_vector_type(8))) short bf16x8;    // 8 bf16 = 4 VGPRs
typedef __attribute__((ext_vector_type(16))) float f32x16;   // 32x32 accumulator

__device__ inline unsigned short f2bf(float f) {             // RNE fp32->bf16
    unsigned u = __float_as_uint(f);
    return (unsigned short)((u + 0x7FFFu + ((u >> 16) & 1u)) >> 16);
}
__device__ inline float bf2f(unsigned short h) {
    return __uint_as_float((unsigned)h << 16);
}
__device__ inline uint4 pack8(unsigned short s0, unsigned short s1,
                              unsigned short s2, unsigned short s3,
                              unsigned short s4, unsigned short s5,
                              unsigned short s6, unsigned short s7) {
    uint4 v;
    v.x = (unsigned)s0 | ((unsigned)s1 << 16);
    v.y = (unsigned)s2 | ((unsigned)s3 << 16);
    v.z = (unsigned)s4 | ((unsigned)s5 << 16);
    v.w = (unsigned)s6 | ((unsigned)s7 << 16);
    return v;
}
__device__ inline bf16x8 as_frag(uint4 v) {
    union { uint4 u; bf16x8 f; } c; c.u = v; return c.f;
}

// DUAL-USE pack: MFMA emits the COMPLETE distance D = |p|^2 + |t|^2 - 2 p.t
// so one tile serves BOTH chamfer directions (row-min AND col-min).
// K=16 slots (same slot convention for A and B -> k-order agnostic):
//   slots 0-2 : ah.th   3-5 : al.th   6-8 : ah.tl
//   slots 9-11: |p|^2 (3-split) . 1     12-14: 1 . |t|^2 (3-split)   15: 0
// Dropped al.tl (RMS ~4e-6/distance, unbiased; mean error ~1e-7 << 3e-4 thr).
__global__ __launch_bounds__(TPB) void prep_kernel(
        const float* __restrict__ a, const float* __restrict__ b,
        uint4* __restrict__ pA, uint4* __restrict__ pB,
        unsigned* __restrict__ pmins,
        float* __restrict__ acc, unsigned* __restrict__ cnt, int n) {
    int idx = blockIdx.x * TPB + threadIdx.x;
    const unsigned short ONE = 0x3F80;
    if (idx < n) {
        // pred -> A-pack (a = -2p, hi/lo split; |p|^2 3-split)
        float x = a[3 * idx], y = a[3 * idx + 1], z = a[3 * idx + 2];
        float w = x * x + y * y + z * z;
        float ax = -2.0f * x, ay = -2.0f * y, az = -2.0f * z;
        unsigned short ahx = f2bf(ax), ahy = f2bf(ay), ahz = f2bf(az);
        unsigned short alx = f2bf(ax - bf2f(ahx));
        unsigned short aly = f2bf(ay - bf2f(ahy));
        unsigned short alz = f2bf(az - bf2f(ahz));
        unsigned short wh = f2bf(w);  float r1 = w - bf2f(wh);
        unsigned short wm = f2bf(r1); float r2 = r1 - bf2f(wm);
        unsigned short wl = f2bf(r2);
        pA[(size_t)idx * 2 + 0] = pack8(ahx, ahy, ahz, alx, aly, alz, ahx, ahy);
        pA[(size_t)idx * 2 + 1] = pack8(ahz, wh, wm, wl, ONE, ONE, ONE, 0);
        pmins[idx] = 0xFFFFFFFFu;
    } else if (idx < 2 * n) {
        // target -> B-pack (t hi/lo split; |t|^2 3-split)
        int i = idx - n;
        float x = b[3 * i], y = b[3 * i + 1], z = b[3 * i + 2];
        float w = x * x + y * y + z * z;
        unsigned short thx = f2bf(x), thy = f2bf(y), thz = f2bf(z);
        unsigned short tlx = f2bf(x - bf2f(thx));
        unsigned short tly = f2bf(y - bf2f(thy));
        unsigned short tlz = f2bf(z - bf2f(thz));
        unsigned short wh = f2bf(w);  float r1 = w - bf2f(wh);
        unsigned short wm = f2bf(r1); float r2 = r1 - bf2f(wm);
        unsigned short wl = f2bf(r2);
        pB[(size_t)i * 2 + 0] = pack8(thx, thy, thz, thx, thy, thz, tlx, tly);
        pB[(size_t)i * 2 + 1] = pack8(tlz, ONE, ONE, ONE, wh, wm, wl, 0);
    }
    if (idx == 0) { acc[0] = 0.0f; cnt[0] = 0u; }
}

// Bidirectional streaming minpass: each 32x32 distance tile is computed ONCE
// and folded into BOTH the row-mins (pred side, registers) and the col-mins
// (target side, per-lane min3-tree over the lane's full column -> LDS
// atomicMin).  Halves MFMA count and L2 B-traffic vs the two-pass scheme
// (R3/R7 plateau at ~32 us was a balanced mix of fold VALU + 256 MB L2
// streaming; this halves the latter two).
//  - col=lane&31 (verified C-layout): lane's 32 regs (d0+d1) are 32 distinct
//    rows of its column; tree + LDS atomic merges lanes/halves/waves.
//  - cm LDS atomics: 32 banks, 2 lanes/bank, no-return -> ~free.
//  - col partials drain with PLAIN stores to cm_out[rbk][col] (each slot
//    written by exactly one block -> no global atomics, no init).
// Block = 4 waves x 64 rows = 256 rows; TS=8 (2048-target slice);
// grid = 64*8 = 512 = 2 blocks/CU; (256,2) -> ~110-reg live set in VGPRs.
__global__ __launch_bounds__(TPB, 2) void minpass_kernel(
        const uint4* __restrict__ pA, const uint4* __restrict__ pB,
        unsigned* __restrict__ pmins, unsigned* __restrict__ cm_out, int n) {
    const int TS = 8;
    const int NRB = n / 256;          // 64 row-blocks
    const int TGT = n / TS;           // 2048 targets per slice
    const int NT = TGT / 32;          // 64 B-tiles per wave

    int bid = blockIdx.x;
    int rbk = bid % NRB;
    int ts  = bid / NRB;

    __shared__ unsigned cm[2048];     // col-min partials (8 KB)

    const int tid = threadIdx.x;
    for (int i = tid; i < TGT; i += TPB) cm[i] = 0xFFFFFFFFu;

    const int wid = tid >> 6, lane = tid & 63;
    const int lr = lane & 31, lh = lane >> 5;

    const int rowbase = rbk * 256 + wid * 64;
    bf16x8 a0 = as_frag(pA[(size_t)(rowbase + lr) * 2 + lh]);
    bf16x8 a1 = as_frag(pA[(size_t)(rowbase + 32 + lr) * 2 + lh]);

    float rm0[16], rm1[16];
#pragma unroll
    for (int i = 0; i < 16; ++i) { rm0[i] = __builtin_inff(); rm1[i] = __builtin_inff(); }
    f32x16 z = {};   // zero C operand

    // lane's B-frag pointer: 32-target tile t at uint4-offset t*64; the
    // wave's 64 lanes cover a contiguous 1KB segment (coalesced dwordx4).
    const uint4* __restrict__ bp = pB + (size_t)(ts * TGT + lr) * 2 + lh;

    __syncthreads();   // cm init visible before first LDS atomic

#define TILE(X, T) do {                                                        \
    bf16x8 bb = as_frag(X);                                                    \
    f32x16 d0 = __builtin_amdgcn_mfma_f32_32x32x16_bf16(a0, bb, z, 0, 0, 0);   \
    f32x16 d1 = __builtin_amdgcn_mfma_f32_32x32x16_bf16(a1, bb, z, 0, 0, 0);   \
    _Pragma("unroll")                                                          \
    for (int i = 0; i < 16; ++i) {                                             \
        rm0[i] = fminf(rm0[i], d0[i]);                                         \
        rm1[i] = fminf(rm1[i], d1[i]);                                         \
    }                                                                          \
    float t8[8];                                                               \
    _Pragma("unroll")                                                          \
    for (int i = 0; i < 8; ++i)                                                \
        t8[i] = fminf(fminf(d0[i], d0[i + 8]), fminf(d1[i], d1[i + 8]));       \
    float c0 = fminf(fminf(t8[0], t8[1]), t8[2]);                              \
    float c1 = fminf(fminf(t8[3], t8[4]), t8[5]);                              \
    float c2 = fminf(t8[6], t8[7]);                                            \
    float cmin = fminf(fminf(c0, c1), c2);                                     \
    atomicMin(&cm[(T) * 32 + lr], __float_as_uint(cmin));                      \
} while (0)

    // rotating 4-tile prefetch (R7's proven pattern): ~3 tile-computes of
    // slack between each load and its use.
    uint4 P0 = bp[0], P1 = bp[64], P2 = bp[128], P3 = bp[192];
    int t = 0;
    for (; t + 4 < NT; t += 4) {
        TILE(P0, t);     P0 = bp[(t + 4) * 64];
        TILE(P1, t + 1); P1 = bp[(t + 5) * 64];
        TILE(P2, t + 2); P2 = bp[(t + 6) * 64];
        TILE(P3, t + 3); P3 = bp[(t + 7) * 64];
    }
    TILE(P0, t); TILE(P1, t + 1); TILE(P2, t + 2); TILE(P3, t + 3);
#undef TILE

    // row-min fold over the 32 columns held by this lane-half
#pragma unroll
    for (int k = 1; k < 32; k <<= 1) {
#pragma unroll
        for (int i = 0; i < 16; ++i) {
            rm0[i] = fminf(rm0[i], __shfl_xor(rm0[i], k, 64));
            rm1[i] = fminf(rm1[i], __shfl_xor(rm1[i], k, 64));
        }
    }
    if (lr == 0) {   // lanes 0 and 32: rows (i&3)+8*(i>>2)+4*lh (+32 for a1)
        int rb0 = rowbase + lh * 4;
#pragma unroll
        for (int i = 0; i < 16; ++i) {
            int r = (i & 3) + ((i >> 2) << 3);
            // full distance already (nonneg, min nn-dist^2 ~1e-1) -> uint-monotone
            atomicMin(&pmins[rb0 + r], __float_as_uint(rm0[i]));
            atomicMin(&pmins[rb0 + 32 + r], __float_as_uint(rm1[i]));
        }
    }

    __syncthreads();   // all waves' cm atomics done
    {
        unsigned* __restrict__ co = cm_out + (size_t)rbk * n + ts * TGT;
        for (int i = tid; i < TGT; i += TPB) co[i] = cm[i];   // plain stores
    }
}

// 32 blocks: 16 reduce the row-mins (uint4 each), 16 reduce the col-min
// partials (4 cols/thread, 64 row-blocks deep).
__global__ __launch_bounds__(TPB) void finalize_kernel(
        const uint4* __restrict__ pmins4, const uint4* __restrict__ cm4,
        float* __restrict__ acc, unsigned* __restrict__ cnt,
        float* __restrict__ out, int n, int nblocks) {
    int b = blockIdx.x;
    float sum;
    if (b < 16) {
        uint4 v = pmins4[b * TPB + threadIdx.x];   // 16*256*4 = n rows
        sum = __uint_as_float(v.x) + __uint_as_float(v.y)
            + __uint_as_float(v.z) + __uint_as_float(v.w);
    } else {
        int c4 = (b - 16) * TPB + threadIdx.x;     // uint4-col index, n/4 total
        const int stride = n / 4;
        uint4 m = cm4[c4];
#pragma unroll
        for (int r = 1; r < 64; ++r) {             // NRB = 64
            uint4 v = cm4[(size_t)r * stride + c4];
            m.x = min(m.x, v.x); m.y = min(m.y, v.y);
            m.z = min(m.z, v.z); m.w = min(m.w, v.w);
        }
        sum = __uint_as_float(m.x) + __uint_as_float(m.y)
            + __uint_as_float(m.z) + __uint_as_float(m.w);
    }
    for (int off = 32; off > 0; off >>= 1)
        sum += __shfl_down(sum, off, 64);
    __shared__ float wsum[TPB / 64];
    int lane = threadIdx.x & 63, wid = threadIdx.x >> 6;
    if (lane == 0) wsum[wid] = sum;
    __syncthreads();
    if (threadIdx.x == 0) {
        float tsum = 0.0f;
        for (int w = 0; w < TPB / 64; ++w) tsum += wsum[w];
        atomicAdd(acc, tsum);
        __threadfence();
        unsigned old = atomicAdd(cnt, 1u);
        if (old == (unsigned)(nblocks - 1)) {
            float a0 = atomicAdd(acc, 0.0f);
            out[0] = a0 / (float)(2 * n);
        }
    }
}

extern "C" void kernel_launch(void* const* d_in, const int* in_sizes, int n_in,
                              void* d_out, int out_size, void* d_ws, size_t ws_size,
                              hipStream_t stream) {
    const float* a = (const float*)d_in[0];
    const float* b = (const float*)d_in[1];
    int n = in_sizes[0] / 3;  // 16384
    float* out = (float*)d_out;
    char* ws = (char*)d_ws;
    float* acc = (float*)ws;                           // 1 float
    unsigned* cnt = (unsigned*)(ws + 8);               // 1 uint
    uint4* pA = (uint4*)(ws + 256);                    // n*32 B = 512 KB
    uint4* pB = (uint4*)(ws + 256 + (size_t)n * 32);   // 512 KB
    unsigned* cm_out = (unsigned*)(ws + 256 + (size_t)n * 64);          // 64*n*4 = 4 MB
    unsigned* pmins = (unsigned*)(ws + 256 + (size_t)n * 64
                                  + (size_t)(n / 256) * n * 4);         // n*4 = 64 KB

    prep_kernel<<<(2 * n + TPB - 1) / TPB, TPB, 0, stream>>>(
        a, b, pA, pB, pmins, acc, cnt, n);
    int mblocks = (n / 256) * 8;                       // 512 = 2 blocks/CU
    minpass_kernel<<<mblocks, TPB, 0, stream>>>(pA, pB, pmins, cm_out, n);
    finalize_kernel<<<32, TPB, 0, stream>>>(
        (const uint4*)pmins, (const uint4*)cm_out, acc, cnt, out, n, 32);
}